// Round 10
// baseline (873.337 us; speedup 1.0000x reference)
//
#include <hip/hip_runtime.h>
#include <hip/hip_bf16.h>
#include <stdint.h>

// CNF step: 4-layer tanh MLP (33->1024->1024->1024->32) forward + exact
// Jacobian trace via 32 forward-mode tangents. B=4096, H=1024, D=32.
// f32 in/out; bf16 MFMA internally.
//
// R10: R9's jvp core measured 1519 TF (73% of 16x16-bf16 ubench ceiling,
// 0 bank conflicts). Two structural moves:
//  - gemm_fwd ported to the SAME 256x128/BK=64/XOR-swizzle/reg-staged core
//    (was the old 128x64 tile, ~2x worse FLOP/LDS-byte). Grid 128 blocks =
//    one ~9us generation.
//  - NB cap raised to 4096: if ws_size permits T0+T1 (536 MB), the jvp
//    chunk loop collapses to a single pass (3 fewer dispatches + tails).

using bf  = __hip_bfloat16;
using bf2 = __hip_bfloat162;
typedef __attribute__((ext_vector_type(8))) short bf16x8;   // 8 bf16 = 4 VGPRs
typedef __attribute__((ext_vector_type(4))) float f32x4;    // C/D frag

__device__ __forceinline__ float b2f(bf x)    { return __bfloat162float(x); }
__device__ __forceinline__ bf    f2b(float x) { return __float2bfloat16(x); }

// ------------------------------------------------------- f32 -> bf16 convert
__global__ __launch_bounds__(256) void conv_k(const float* __restrict__ src,
                                              bf* __restrict__ dst, int n4) {
  const int i = blockIdx.x * 256 + threadIdx.x;
  if (i >= n4) return;
  float4 v = ((const float4*)src)[i];
  bf2* d = (bf2*)(dst + (size_t)i * 4);
  d[0] = __float22bfloat162_rn(make_float2(v.x, v.y));
  d[1] = __float22bfloat162_rn(make_float2(v.z, v.w));
}

// ------------------------------------------------- W0T bf16 (32x1024) from f32
__global__ void w0t_k(const float* __restrict__ W0, bf* __restrict__ W0T) {
  const int idx = blockIdx.x * 256 + threadIdx.x;  // 32768 total
  const int i = idx >> 10, q = idx & 1023;
  W0T[idx] = f2b(W0[q * 33 + i]);
}

// ---------------------------------------------------------------- fwd0
__global__ __launch_bounds__(256) void fwd0_k(const float* __restrict__ z,
                                              const float* __restrict__ tin,
                                              const float* __restrict__ W0,
                                              const float* __restrict__ b0,
                                              bf* __restrict__ h0) {
  __shared__ float zs[32 * 33];  // [s][k], k=32 is t
  const int t = threadIdx.x;
  const int s0 = blockIdx.x * 32;
  for (int j = t; j < 1024; j += 256) {
    const int s = j >> 5, k = j & 31;
    zs[s * 33 + k] = z[(size_t)(s0 + s) * 32 + k];
  }
  if (t < 32) zs[t * 33 + 32] = tin[0];
  __syncthreads();
#pragma unroll 1
  for (int rep = 0; rep < 4; ++rep) {
    const int hh = rep * 256 + t;
    const float* wr = W0 + (size_t)hh * 33;
    float wv[33];
#pragma unroll
    for (int k = 0; k < 33; ++k) wv[k] = wr[k];
    const float bv = b0[hh];
#pragma unroll 1
    for (int s = 0; s < 32; ++s) {
      float acc = bv;
#pragma unroll
      for (int k = 0; k < 33; ++k) acc += wv[k] * zs[s * 33 + k];
      h0[(size_t)(s0 + s) * 1024 + hh] = f2b(tanhf(acc));
    }
  }
}

// ---------------------------------------------------------------- fwd GEMM
// H[m][n] = tanh(sum_k A[m][k]*W[n][k] + bias[n]); M=4096, N=K=1024.
// R9 core: 256x128 block, 128x64 wave-tile, BK=64, XOR-swizzle pitch-64,
// register-staged two-barrier loop. Grid = 128 blocks.
__global__ __launch_bounds__(256, 2) void gemm_fwd(const bf* __restrict__ A,
                                                   const bf* __restrict__ W,
                                                   const float* __restrict__ bias,
                                                   bf* __restrict__ H) {
  constexpr int K = 1024, N = 1024;
  __shared__ __align__(16) bf As[256 * 64];   // 32 KB
  __shared__ __align__(16) bf Bs[128 * 64];   // 16 KB
  const int t = threadIdx.x, l = t & 63, w = t >> 6;
  const int wm = w >> 1, wn = w & 1;
  const int f = blockIdx.x;                   // 128 blocks: 16 m x 8 n
  const int n_t = (f >> 3) & 7, m_t = (f & 7) + 8 * (f >> 6);
  const size_t m0 = (size_t)m_t * 256, n0 = (size_t)n_t * 128;
  const int r15 = l & 15, q4 = l >> 4, sw = r15 & 7;

  const bf* asrc[8]; int aoff[8];
  const bf* bsrc[4]; int boff[4];
#pragma unroll
  for (int u = 0; u < 8; ++u) {
    const int sidx = u * 256 + t, row = sidx >> 3, seg = sidx & 7;
    asrc[u] = A + (m0 + row) * K + seg * 8;
    aoff[u] = row * 64 + ((seg ^ (row & 7)) * 8);
  }
#pragma unroll
  for (int u = 0; u < 4; ++u) {
    const int sidx = u * 256 + t, row = sidx >> 3, seg = sidx & 7;
    bsrc[u] = W + (n0 + row) * K + seg * 8;
    boff[u] = row * 64 + ((seg ^ (row & 7)) * 8);
  }

  f32x4 acc[8][4] = {};

  auto compute = [&]() {
#pragma unroll
    for (int kk = 0; kk < 2; ++kk) {
      const int sa = (kk * 4 + q4) ^ sw;
      bf16x8 af[8], bfr[4];
#pragma unroll
      for (int i = 0; i < 8; ++i)
        af[i] = *(const bf16x8*)(As + (wm * 128 + i * 16 + r15) * 64 + sa * 8);
#pragma unroll
      for (int j = 0; j < 4; ++j)
        bfr[j] = *(const bf16x8*)(Bs + (wn * 64 + j * 16 + r15) * 64 + sa * 8);
#pragma unroll
      for (int mi = 0; mi < 8; ++mi)
#pragma unroll
        for (int ni = 0; ni < 4; ++ni)
          acc[mi][ni] = __builtin_amdgcn_mfma_f32_16x16x32_bf16(af[mi], bfr[ni], acc[mi][ni], 0, 0, 0);
    }
  };

  {  // prologue: stage k=0
    bf16x8 ra[8], rb[4];
#pragma unroll
    for (int u = 0; u < 8; ++u) ra[u] = *(const bf16x8*)(asrc[u]);
#pragma unroll
    for (int u = 0; u < 4; ++u) rb[u] = *(const bf16x8*)(bsrc[u]);
#pragma unroll
    for (int u = 0; u < 8; ++u) *(bf16x8*)(As + aoff[u]) = ra[u];
#pragma unroll
    for (int u = 0; u < 4; ++u) *(bf16x8*)(Bs + boff[u]) = rb[u];
  }
  __syncthreads();
#pragma unroll 1
  for (int k0 = 64; k0 < K; k0 += 64) {
    bf16x8 ra[8], rb[4];
#pragma unroll
    for (int u = 0; u < 8; ++u) ra[u] = *(const bf16x8*)(asrc[u] + k0);
#pragma unroll
    for (int u = 0; u < 4; ++u) rb[u] = *(const bf16x8*)(bsrc[u] + k0);
    compute();
    __syncthreads();
#pragma unroll
    for (int u = 0; u < 8; ++u) *(bf16x8*)(As + aoff[u]) = ra[u];
#pragma unroll
    for (int u = 0; u < 4; ++u) *(bf16x8*)(Bs + boff[u]) = rb[u];
    __syncthreads();
  }
  compute();

#pragma unroll
  for (int ni = 0; ni < 4; ++ni) {
    const int n = (int)n0 + wn * 64 + ni * 16 + r15;
    const float bv = bias[n];
#pragma unroll
    for (int mi = 0; mi < 8; ++mi)
#pragma unroll
      for (int r = 0; r < 4; ++r) {
        const size_t m = m0 + wm * 128 + mi * 16 + q4 * 4 + r;
        H[m * N + n] = f2b(tanhf(acc[mi][ni][r] + bv));
      }
  }
}

// ---------------------------------------------------------------- fwd3 (out)
__global__ __launch_bounds__(256) void fwd3_k(const bf* __restrict__ h2,
                                              const bf* __restrict__ W3b,
                                              const float* __restrict__ b3,
                                              float* __restrict__ out) {
  __shared__ __align__(16) bf hs[8 * 1024];
  const int t = threadIdx.x;
  const size_t bb = (size_t)blockIdx.x * 8;
  const uint4* src = (const uint4*)(h2 + bb * 1024);
  uint4* dv = (uint4*)hs;
#pragma unroll
  for (int j = 0; j < 4; ++j) dv[j * 256 + t] = src[j * 256 + t];
  __syncthreads();
  const int i = t & 31, bl = t >> 5;
  const bf2* hr = (const bf2*)(hs + bl * 1024);
  const bf2* wr = (const bf2*)(W3b + (size_t)i * 1024);
  float s = 0.f;
#pragma unroll 8
  for (int k2 = 0; k2 < 512; ++k2) {
    float2 a = __bfloat1622float2(hr[k2]);
    float2 c = __bfloat1622float2(wr[k2]);
    s += a.x * c.x + a.y * c.y;
  }
  out[(bb + bl) * 32 + i] = s + b3[i];
}

// ---------------------------------------------------------------- t0 build
// T0[(b,i)][q] = (1-h0[b,q]^2)*W0T[i,q], chunk-local rows. Streaming VALU.
__global__ __launch_bounds__(256) void t0_k(const bf* __restrict__ h0c,
                                            const bf* __restrict__ W0T,
                                            bf* __restrict__ T0) {
  const int idx = blockIdx.x * 256 + threadIdx.x;
  const int m = idx >> 6, seg = idx & 63;
  const int b = m >> 5, i = m & 31;
  const bf2* hp = (const bf2*)(h0c + (size_t)b * 1024 + seg * 16);
  const bf2* wp = (const bf2*)(W0T + (size_t)i * 1024 + seg * 16);
  bf2* dp = (bf2*)(T0 + (size_t)m * 1024 + seg * 16);
#pragma unroll
  for (int u = 0; u < 8; ++u) {
    float2 h = __bfloat1622float2(hp[u]);
    float2 w = __bfloat1622float2(wp[u]);
    float2 r;
    r.x = (1.f - h.x * h.x) * w.x;
    r.y = (1.f - h.y * h.y) * w.y;
    dp[u] = __float22bfloat162_rn(r);
  }
}

// ---------------------------------------------------------------- jvp1
// T1[m][n] = (1-h1[b,n]^2)*sum_q T0[m][q]*W1[n,q].  (R9 core, unchanged)
__global__ __launch_bounds__(256, 2) void gemm_jvp1(const bf* __restrict__ T0,
                                                    const bf* __restrict__ W1b,
                                                    const bf* __restrict__ h1c,
                                                    bf* __restrict__ T1) {
  constexpr int K = 1024, N = 1024;
  __shared__ __align__(16) bf As[256 * 64];   // 32 KB
  __shared__ __align__(16) bf Bs[128 * 64];   // 16 KB
  const int t = threadIdx.x, l = t & 63, w = t >> 6;
  const int wm = w >> 1, wn = w & 1;
  const int f = blockIdx.x;
  const int n_t = (f >> 3) & 7, m_t = (f & 7) + 8 * (f >> 6);
  const size_t m0 = (size_t)m_t * 256, n0 = (size_t)n_t * 128;
  const int r15 = l & 15, q4 = l >> 4, sw = r15 & 7;

  const bf* asrc[8]; int aoff[8];
  const bf* bsrc[4]; int boff[4];
#pragma unroll
  for (int u = 0; u < 8; ++u) {
    const int sidx = u * 256 + t, row = sidx >> 3, seg = sidx & 7;
    asrc[u] = T0 + (m0 + row) * K + seg * 8;
    aoff[u] = row * 64 + ((seg ^ (row & 7)) * 8);
  }
#pragma unroll
  for (int u = 0; u < 4; ++u) {
    const int sidx = u * 256 + t, row = sidx >> 3, seg = sidx & 7;
    bsrc[u] = W1b + (n0 + row) * K + seg * 8;
    boff[u] = row * 64 + ((seg ^ (row & 7)) * 8);
  }

  f32x4 acc[8][4] = {};

  auto compute = [&]() {
#pragma unroll
    for (int kk = 0; kk < 2; ++kk) {
      const int sa = (kk * 4 + q4) ^ sw;
      bf16x8 af[8], bfr[4];
#pragma unroll
      for (int i = 0; i < 8; ++i)
        af[i] = *(const bf16x8*)(As + (wm * 128 + i * 16 + r15) * 64 + sa * 8);
#pragma unroll
      for (int j = 0; j < 4; ++j)
        bfr[j] = *(const bf16x8*)(Bs + (wn * 64 + j * 16 + r15) * 64 + sa * 8);
#pragma unroll
      for (int mi = 0; mi < 8; ++mi)
#pragma unroll
        for (int ni = 0; ni < 4; ++ni)
          acc[mi][ni] = __builtin_amdgcn_mfma_f32_16x16x32_bf16(af[mi], bfr[ni], acc[mi][ni], 0, 0, 0);
    }
  };

  {  // prologue: stage k=0
    bf16x8 ra[8], rb[4];
#pragma unroll
    for (int u = 0; u < 8; ++u) ra[u] = *(const bf16x8*)(asrc[u]);
#pragma unroll
    for (int u = 0; u < 4; ++u) rb[u] = *(const bf16x8*)(bsrc[u]);
#pragma unroll
    for (int u = 0; u < 8; ++u) *(bf16x8*)(As + aoff[u]) = ra[u];
#pragma unroll
    for (int u = 0; u < 4; ++u) *(bf16x8*)(Bs + boff[u]) = rb[u];
  }
  __syncthreads();
#pragma unroll 1
  for (int k0 = 64; k0 < K; k0 += 64) {
    bf16x8 ra[8], rb[4];
#pragma unroll
    for (int u = 0; u < 8; ++u) ra[u] = *(const bf16x8*)(asrc[u] + k0);
#pragma unroll
    for (int u = 0; u < 4; ++u) rb[u] = *(const bf16x8*)(bsrc[u] + k0);
    compute();
    __syncthreads();
#pragma unroll
    for (int u = 0; u < 8; ++u) *(bf16x8*)(As + aoff[u]) = ra[u];
#pragma unroll
    for (int u = 0; u < 4; ++u) *(bf16x8*)(Bs + boff[u]) = rb[u];
    __syncthreads();
  }
  compute();

  const int bbase = (int)((m0 + wm * 128) >> 5);  // 4 samples per wave
#pragma unroll
  for (int ni = 0; ni < 4; ++ni) {
    const int n = (int)n0 + wn * 64 + ni * 16 + r15;
    float a1v[4];
#pragma unroll
    for (int s = 0; s < 4; ++s) {
      const float hv = b2f(h1c[(size_t)(bbase + s) * 1024 + n]);
      a1v[s] = 1.f - hv * hv;
    }
#pragma unroll
    for (int mi = 0; mi < 8; ++mi)
#pragma unroll
      for (int r = 0; r < 4; ++r) {
        const size_t m = m0 + wm * 128 + mi * 16 + q4 * 4 + r;
        T1[m * N + n] = f2b(a1v[mi >> 1] * acc[mi][ni][r]);
      }
  }
}

// ---------------------------------------------------------------- jvp2
// U2 = W2 @ T1; trace[b] -= sum_{p,i} W3[i,p]*(1-h2[b,p]^2)*U2[p,(b,i)]
__global__ __launch_bounds__(256, 2) void gemm_jvp2(const bf* __restrict__ T1,
                                                    const bf* __restrict__ W2b,
                                                    const bf* __restrict__ W3b,
                                                    const bf* __restrict__ h2c,
                                                    float* __restrict__ trace) {
  constexpr int K = 1024;
  __shared__ __align__(16) bf As[256 * 64];
  __shared__ __align__(16) bf Bs[128 * 64];
  const int t = threadIdx.x, l = t & 63, w = t >> 6;
  const int wm = w >> 1, wn = w & 1;
  const int f = blockIdx.x;
  const int n_t = (f >> 3) & 7, m_t = (f & 7) + 8 * (f >> 6);
  const size_t m0 = (size_t)m_t * 256, n0 = (size_t)n_t * 128;
  const int r15 = l & 15, q4 = l >> 4, sw = r15 & 7;

  const bf* asrc[8]; int aoff[8];
  const bf* bsrc[4]; int boff[4];
#pragma unroll
  for (int u = 0; u < 8; ++u) {
    const int sidx = u * 256 + t, row = sidx >> 3, seg = sidx & 7;
    asrc[u] = T1 + (m0 + row) * K + seg * 8;
    aoff[u] = row * 64 + ((seg ^ (row & 7)) * 8);
  }
#pragma unroll
  for (int u = 0; u < 4; ++u) {
    const int sidx = u * 256 + t, row = sidx >> 3, seg = sidx & 7;
    bsrc[u] = W2b + (n0 + row) * K + seg * 8;
    boff[u] = row * 64 + ((seg ^ (row & 7)) * 8);
  }

  f32x4 acc[8][4] = {};

  auto compute = [&]() {
#pragma unroll
    for (int kk = 0; kk < 2; ++kk) {
      const int sa = (kk * 4 + q4) ^ sw;
      bf16x8 af[8], bfr[4];
#pragma unroll
      for (int i = 0; i < 8; ++i)
        af[i] = *(const bf16x8*)(As + (wm * 128 + i * 16 + r15) * 64 + sa * 8);
#pragma unroll
      for (int j = 0; j < 4; ++j)
        bfr[j] = *(const bf16x8*)(Bs + (wn * 64 + j * 16 + r15) * 64 + sa * 8);
#pragma unroll
      for (int mi = 0; mi < 8; ++mi)
#pragma unroll
        for (int ni = 0; ni < 4; ++ni)
          acc[mi][ni] = __builtin_amdgcn_mfma_f32_16x16x32_bf16(af[mi], bfr[ni], acc[mi][ni], 0, 0, 0);
    }
  };

  {  // prologue
    bf16x8 ra[8], rb[4];
#pragma unroll
    for (int u = 0; u < 8; ++u) ra[u] = *(const bf16x8*)(asrc[u]);
#pragma unroll
    for (int u = 0; u < 4; ++u) rb[u] = *(const bf16x8*)(bsrc[u]);
#pragma unroll
    for (int u = 0; u < 8; ++u) *(bf16x8*)(As + aoff[u]) = ra[u];
#pragma unroll
    for (int u = 0; u < 4; ++u) *(bf16x8*)(Bs + boff[u]) = rb[u];
  }
  __syncthreads();
#pragma unroll 1
  for (int k0 = 64; k0 < K; k0 += 64) {
    bf16x8 ra[8], rb[4];
#pragma unroll
    for (int u = 0; u < 8; ++u) ra[u] = *(const bf16x8*)(asrc[u] + k0);
#pragma unroll
    for (int u = 0; u < 4; ++u) rb[u] = *(const bf16x8*)(bsrc[u] + k0);
    compute();
    __syncthreads();
#pragma unroll
    for (int u = 0; u < 8; ++u) *(bf16x8*)(As + aoff[u]) = ra[u];
#pragma unroll
    for (int u = 0; u < 4; ++u) *(bf16x8*)(Bs + boff[u]) = rb[u];
    __syncthreads();
  }
  compute();

  const int bbase = (int)((m0 + wm * 128) >> 5);  // 4 samples per wave
  float part[4] = {0.f, 0.f, 0.f, 0.f};
#pragma unroll
  for (int ni = 0; ni < 4; ++ni) {
    const int n = (int)n0 + wn * 64 + ni * 16 + r15;  // = p
    float a2v[4];
#pragma unroll
    for (int s = 0; s < 4; ++s) {
      const float hv = b2f(h2c[(size_t)(bbase + s) * 1024 + n]);
      a2v[s] = 1.f - hv * hv;
    }
#pragma unroll
    for (int mi = 0; mi < 8; ++mi) {
      const int isel = mi >> 1;
#pragma unroll
      for (int r = 0; r < 4; ++r) {
        const int mm = wm * 128 + mi * 16 + q4 * 4 + r;  // i = mm & 31
        part[isel] += b2f(W3b[(size_t)(mm & 31) * 1024 + n]) * a2v[isel] * acc[mi][ni][r];
      }
    }
  }
#pragma unroll
  for (int off = 32; off > 0; off >>= 1) {
#pragma unroll
    for (int s = 0; s < 4; ++s) part[s] += __shfl_down(part[s], off);
  }
  if (l == 0) {
#pragma unroll
    for (int s = 0; s < 4; ++s) atomicAdd(trace + bbase + s, -part[s]);
  }
}

// ---------------------------------------------------------------- divv
__global__ void divv_k(const float* __restrict__ tr, float* __restrict__ dv) {
  const int b = blockIdx.x * 256 + threadIdx.x;
  dv[b] = tr[b];
}

// ================================================================ launch
extern "C" void kernel_launch(void* const* d_in, const int* in_sizes, int n_in,
                              void* d_out, int out_size, void* d_ws, size_t ws_size,
                              hipStream_t stream) {
  const float* tin = (const float*)d_in[0];
  const float* z   = (const float*)d_in[1];
  const float* W0  = (const float*)d_in[2];
  const float* b0  = (const float*)d_in[3];
  const float* W1  = (const float*)d_in[4];
  const float* b1  = (const float*)d_in[5];
  const float* W2  = (const float*)d_in[6];
  const float* b2  = (const float*)d_in[7];
  const float* W3  = (const float*)d_in[8];
  const float* b3  = (const float*)d_in[9];
  float* out = (float*)d_out;
  (void)in_sizes; (void)n_in; (void)out_size;

  char* ws = (char*)d_ws;
  size_t off = 0;
  auto take = [&](size_t bytes) {
    char* p = ws + off;
    off = (off + bytes + 255) & ~(size_t)255;
    return p;
  };
  bf* h0   = (bf*)take((size_t)4096 * 1024 * 2);   // 8 MB
  bf* h1   = (bf*)take((size_t)4096 * 1024 * 2);   // 8 MB
  bf* h2   = (bf*)take((size_t)4096 * 1024 * 2);   // 8 MB
  bf* W0T  = (bf*)take((size_t)32 * 1024 * 2);     // 64 KB
  bf* W1b  = (bf*)take((size_t)1024 * 1024 * 2);   // 2 MB
  bf* W2b  = (bf*)take((size_t)1024 * 1024 * 2);   // 2 MB
  bf* W3b  = (bf*)take((size_t)32 * 1024 * 2);     // 64 KB
  float* tr = (float*)take((size_t)4096 * 4);      // 16 KB
  // chunk size: T0 + T1, each NB*32*1024*2 bytes; NB multiple of 8
  const size_t avail = (ws_size > off) ? (ws_size - off) : 0;
  int NB = 4096;
  while (NB > 256 && 2 * (size_t)NB * 65536 > avail) NB >>= 1;
  bf* T0 = (bf*)take((size_t)NB * 65536);
  bf* T1 = (bf*)take((size_t)NB * 65536);

  hipMemsetAsync(tr, 0, 4096 * sizeof(float), stream);
  conv_k<<<dim3(1024), dim3(256), 0, stream>>>(W1, W1b, 262144);
  conv_k<<<dim3(1024), dim3(256), 0, stream>>>(W2, W2b, 262144);
  conv_k<<<dim3(32),   dim3(256), 0, stream>>>(W3, W3b, 8192);
  w0t_k<<<dim3(128), dim3(256), 0, stream>>>(W0, W0T);
  fwd0_k<<<dim3(128), dim3(256), 0, stream>>>(z, tin, W0, b0, h0);
  gemm_fwd<<<dim3(128), dim3(256), 0, stream>>>(h0, W1b, b1, h1);
  gemm_fwd<<<dim3(128), dim3(256), 0, stream>>>(h1, W2b, b2, h2);
  fwd3_k<<<dim3(512), dim3(256), 0, stream>>>(h2, W3b, b3, out);
  for (int cb = 0; cb < 4096; cb += NB) {
    t0_k<<<dim3(NB * 8), dim3(256), 0, stream>>>(h0 + (size_t)cb * 1024, W0T, T0);
    gemm_jvp1<<<dim3(NB), dim3(256), 0, stream>>>(
        T0, W1b, h1 + (size_t)cb * 1024, T1);
    gemm_jvp2<<<dim3(NB), dim3(256), 0, stream>>>(
        T1, W2b, W3b, h2 + (size_t)cb * 1024, tr + cb);
  }
  divv_k<<<dim3(16), dim3(256), 0, stream>>>(tr, out + 131072);
}

// Round 11
// 855.047 us; speedup vs baseline: 1.0214x; 1.0214x over previous
//
#include <hip/hip_runtime.h>
#include <hip/hip_bf16.h>
#include <stdint.h>

// CNF step: 4-layer tanh MLP (33->1024->1024->1024->32) forward + exact
// Jacobian trace via 32 forward-mode tangents. B=4096, H=1024, D=32.
// f32 in/out; bf16 MFMA internally.
//
// R11: dispatch-count collapse 15 -> 7. Kernel-time sum (~520us) vs measured
// total (873us) shows ~350us of per-dispatch overhead/gaps. Merge:
//   prep_k   = fwd0 + conv(W1,W2,W3) + W0T + zero divv region   [1 dispatch]
//   fwd_t0_k = gemm_fwd(128 blocks, half the CUs) + t0 chunk0 blocks
//              (t0's streaming fills the idle half)
//   jvp1 c0  + fwd3 merged (LDS overlaid, occupancy unchanged)
//   jvp2 c   + t0(c+1) merged (T0 reusable once jvp1(c) done)
//   divv+memset deleted: jvp2 atomics write -trace into out+131072,
//   zeroed by prep.
// GEMM cores byte-identical to R10 (0 bank conflicts, ~1560 TF jvp).

using bf  = __hip_bfloat16;
using bf2 = __hip_bfloat162;
typedef __attribute__((ext_vector_type(8))) short bf16x8;   // 8 bf16 = 4 VGPRs
typedef __attribute__((ext_vector_type(4))) float f32x4;    // C/D frag

__device__ __forceinline__ float b2f(bf x)    { return __bfloat162float(x); }
__device__ __forceinline__ bf    f2b(float x) { return __float2bfloat16(x); }

// ---------------------------------------------------------------- bodies
__device__ __forceinline__ void conv_body(int blk, const float* __restrict__ src,
                                          bf* __restrict__ dst, int n4) {
  const int i = blk * 256 + threadIdx.x;
  if (i >= n4) return;
  float4 v = ((const float4*)src)[i];
  bf2* d = (bf2*)(dst + (size_t)i * 4);
  d[0] = __float22bfloat162_rn(make_float2(v.x, v.y));
  d[1] = __float22bfloat162_rn(make_float2(v.z, v.w));
}

__device__ __forceinline__ void w0t_body(int blk, const float* __restrict__ W0,
                                         bf* __restrict__ W0T) {
  const int idx = blk * 256 + threadIdx.x;
  const int i = idx >> 10, q = idx & 1023;
  W0T[idx] = f2b(W0[q * 33 + i]);
}

__device__ __forceinline__ void t0_body(int blk, const bf* __restrict__ h0c,
                                        const bf* __restrict__ W0T,
                                        bf* __restrict__ T0) {
  const int idx = blk * 256 + threadIdx.x;
  const int m = idx >> 6, seg = idx & 63;
  const int b = m >> 5, i = m & 31;
  const bf2* hp = (const bf2*)(h0c + (size_t)b * 1024 + seg * 16);
  const bf2* wp = (const bf2*)(W0T + (size_t)i * 1024 + seg * 16);
  bf2* dp = (bf2*)(T0 + (size_t)m * 1024 + seg * 16);
#pragma unroll
  for (int u = 0; u < 8; ++u) {
    float2 h = __bfloat1622float2(hp[u]);
    float2 w = __bfloat1622float2(wp[u]);
    float2 r;
    r.x = (1.f - h.x * h.x) * w.x;
    r.y = (1.f - h.y * h.y) * w.y;
    dp[u] = __float22bfloat162_rn(r);
  }
}

// 256x128 block, 128x64 wave-tile, BK=64, XOR-swizzle pitch-64, reg-staged.
__device__ __forceinline__ void gemm_core(bf* As, bf* Bs,
                                          const bf* __restrict__ A,
                                          const bf* __restrict__ B,
                                          size_t m0, size_t n0,
                                          f32x4 (&acc)[8][4]) {
  constexpr int K = 1024;
  const int t = threadIdx.x, l = t & 63, w = t >> 6;
  const int wm = w >> 1, wn = w & 1;
  const int r15 = l & 15, q4 = l >> 4, sw = r15 & 7;

  const bf* asrc[8]; int aoff[8];
  const bf* bsrc[4]; int boff[4];
#pragma unroll
  for (int u = 0; u < 8; ++u) {
    const int sidx = u * 256 + t, row = sidx >> 3, seg = sidx & 7;
    asrc[u] = A + (m0 + row) * K + seg * 8;
    aoff[u] = row * 64 + ((seg ^ (row & 7)) * 8);
  }
#pragma unroll
  for (int u = 0; u < 4; ++u) {
    const int sidx = u * 256 + t, row = sidx >> 3, seg = sidx & 7;
    bsrc[u] = B + (n0 + row) * K + seg * 8;
    boff[u] = row * 64 + ((seg ^ (row & 7)) * 8);
  }

  auto compute = [&]() {
#pragma unroll
    for (int kk = 0; kk < 2; ++kk) {
      const int sa = (kk * 4 + q4) ^ sw;
      bf16x8 af[8], bfr[4];
#pragma unroll
      for (int i = 0; i < 8; ++i)
        af[i] = *(const bf16x8*)(As + (wm * 128 + i * 16 + r15) * 64 + sa * 8);
#pragma unroll
      for (int j = 0; j < 4; ++j)
        bfr[j] = *(const bf16x8*)(Bs + (wn * 64 + j * 16 + r15) * 64 + sa * 8);
#pragma unroll
      for (int mi = 0; mi < 8; ++mi)
#pragma unroll
        for (int ni = 0; ni < 4; ++ni)
          acc[mi][ni] = __builtin_amdgcn_mfma_f32_16x16x32_bf16(af[mi], bfr[ni], acc[mi][ni], 0, 0, 0);
    }
  };

  {  // prologue: stage k=0
    bf16x8 ra[8], rb[4];
#pragma unroll
    for (int u = 0; u < 8; ++u) ra[u] = *(const bf16x8*)(asrc[u]);
#pragma unroll
    for (int u = 0; u < 4; ++u) rb[u] = *(const bf16x8*)(bsrc[u]);
#pragma unroll
    for (int u = 0; u < 8; ++u) *(bf16x8*)(As + aoff[u]) = ra[u];
#pragma unroll
    for (int u = 0; u < 4; ++u) *(bf16x8*)(Bs + boff[u]) = rb[u];
  }
  __syncthreads();
#pragma unroll 1
  for (int k0 = 64; k0 < K; k0 += 64) {
    bf16x8 ra[8], rb[4];
#pragma unroll
    for (int u = 0; u < 8; ++u) ra[u] = *(const bf16x8*)(asrc[u] + k0);
#pragma unroll
    for (int u = 0; u < 4; ++u) rb[u] = *(const bf16x8*)(bsrc[u] + k0);
    compute();
    __syncthreads();
#pragma unroll
    for (int u = 0; u < 8; ++u) *(bf16x8*)(As + aoff[u]) = ra[u];
#pragma unroll
    for (int u = 0; u < 4; ++u) *(bf16x8*)(Bs + boff[u]) = rb[u];
    __syncthreads();
  }
  compute();
}

__device__ __forceinline__ void fwd3_body(bf* hs, int blk,
                                          const bf* __restrict__ h2,
                                          const bf* __restrict__ W3b,
                                          const float* __restrict__ b3,
                                          float* __restrict__ out) {
  const int t = threadIdx.x;
  const size_t bb = (size_t)blk * 8;
  const uint4* src = (const uint4*)(h2 + bb * 1024);
  uint4* dv = (uint4*)hs;
#pragma unroll
  for (int j = 0; j < 4; ++j) dv[j * 256 + t] = src[j * 256 + t];
  __syncthreads();
  const int i = t & 31, bl = t >> 5;
  const bf2* hr = (const bf2*)(hs + bl * 1024);
  const bf2* wr = (const bf2*)(W3b + (size_t)i * 1024);
  float s = 0.f;
#pragma unroll 8
  for (int k2 = 0; k2 < 512; ++k2) {
    float2 a = __bfloat1622float2(hr[k2]);
    float2 c = __bfloat1622float2(wr[k2]);
    s += a.x * c.x + a.y * c.y;
  }
  out[(bb + bl) * 32 + i] = s + b3[i];
}

// ---------------------------------------------------------------- prep
// blocks [0,128): fwd0 | [128,1152): conv W1 | [1152,2176): conv W2
// [2176,2208): conv W3 | [2208,2336): W0T | 2336: zero divv region
__global__ __launch_bounds__(256) void prep_k(const float* __restrict__ z,
                                              const float* __restrict__ tin,
                                              const float* __restrict__ W0,
                                              const float* __restrict__ b0,
                                              const float* __restrict__ W1,
                                              const float* __restrict__ W2,
                                              const float* __restrict__ W3,
                                              bf* __restrict__ h0,
                                              bf* __restrict__ W0T,
                                              bf* __restrict__ W1b,
                                              bf* __restrict__ W2b,
                                              bf* __restrict__ W3b,
                                              float* __restrict__ out2) {
  __shared__ float zs[32 * 33];
  const int f = blockIdx.x, t = threadIdx.x;
  if (f < 128) {  // fwd0: 32 samples/block
    const int s0 = f * 32;
    for (int j = t; j < 1024; j += 256) {
      const int s = j >> 5, k = j & 31;
      zs[s * 33 + k] = z[(size_t)(s0 + s) * 32 + k];
    }
    if (t < 32) zs[t * 33 + 32] = tin[0];
    __syncthreads();
#pragma unroll 1
    for (int rep = 0; rep < 4; ++rep) {
      const int hh = rep * 256 + t;
      const float* wr = W0 + (size_t)hh * 33;
      float wv[33];
#pragma unroll
      for (int k = 0; k < 33; ++k) wv[k] = wr[k];
      const float bv = b0[hh];
#pragma unroll 1
      for (int s = 0; s < 32; ++s) {
        float acc = bv;
#pragma unroll
        for (int k = 0; k < 33; ++k) acc += wv[k] * zs[s * 33 + k];
        h0[(size_t)(s0 + s) * 1024 + hh] = f2b(tanhf(acc));
      }
    }
  } else if (f < 1152) {
    conv_body(f - 128, W1, W1b, 262144);
  } else if (f < 2176) {
    conv_body(f - 1152, W2, W2b, 262144);
  } else if (f < 2208) {
    conv_body(f - 2176, W3, W3b, 8192);
  } else if (f < 2336) {
    w0t_body(f - 2208, W0, W0T);
  } else {
#pragma unroll
    for (int u = 0; u < 16; ++u) out2[u * 256 + t] = 0.f;
  }
}

// ---------------------------------------------------------------- fwd GEMM + t0
// blocks [0,128): H = tanh(A @ W^T + bias); rest: t0 chunk build.
__global__ __launch_bounds__(256, 2) void fwd_t0_k(const bf* __restrict__ A,
                                                   const bf* __restrict__ W,
                                                   const float* __restrict__ bias,
                                                   bf* __restrict__ H,
                                                   const bf* __restrict__ h0c,
                                                   const bf* __restrict__ W0T,
                                                   bf* __restrict__ T0) {
  __shared__ __align__(16) bf smem[24576];  // 48 KB: As 16384 + Bs 8192
  const int f = blockIdx.x;
  if (f >= 128) { t0_body(f - 128, h0c, W0T, T0); return; }
  constexpr int N = 1024;
  const int t = threadIdx.x, l = t & 63, w = t >> 6;
  const int wm = w >> 1, wn = w & 1;
  const int n_t = (f >> 3) & 7, m_t = (f & 7) + 8 * (f >> 6);
  const size_t m0 = (size_t)m_t * 256, n0 = (size_t)n_t * 128;
  const int r15 = l & 15, q4 = l >> 4;
  f32x4 acc[8][4] = {};
  gemm_core(smem, smem + 16384, A, W, m0, n0, acc);
#pragma unroll
  for (int ni = 0; ni < 4; ++ni) {
    const int n = (int)n0 + wn * 64 + ni * 16 + r15;
    const float bv = bias[n];
#pragma unroll
    for (int mi = 0; mi < 8; ++mi)
#pragma unroll
      for (int r = 0; r < 4; ++r) {
        const size_t m = m0 + wm * 128 + mi * 16 + q4 * 4 + r;
        H[m * N + n] = f2b(tanhf(acc[mi][ni][r] + bv));
      }
  }
}

// ---------------------------------------------------------------- jvp1 + fwd3
// blocks [0,njvp): T1 = diag(1-h1^2)(T0 @ W1^T); [njvp,..): fwd3 out.
__global__ __launch_bounds__(256, 2) void jvp1_fwd3_k(const bf* __restrict__ T0,
                                                      const bf* __restrict__ W1b,
                                                      const bf* __restrict__ h1c,
                                                      bf* __restrict__ T1,
                                                      const bf* __restrict__ h2,
                                                      const bf* __restrict__ W3b,
                                                      const float* __restrict__ b3,
                                                      float* __restrict__ out,
                                                      int njvp) {
  __shared__ __align__(16) bf smem[24576];
  const int f = blockIdx.x;
  if (f >= njvp) { fwd3_body(smem, f - njvp, h2, W3b, b3, out); return; }
  constexpr int N = 1024;
  const int t = threadIdx.x, l = t & 63, w = t >> 6;
  const int wm = w >> 1, wn = w & 1;
  const int n_t = (f >> 3) & 7, m_t = (f & 7) + 8 * (f >> 6);
  const size_t m0 = (size_t)m_t * 256, n0 = (size_t)n_t * 128;
  const int r15 = l & 15, q4 = l >> 4;
  f32x4 acc[8][4] = {};
  gemm_core(smem, smem + 16384, T0, W1b, m0, n0, acc);
  const int bbase = (int)((m0 + wm * 128) >> 5);
#pragma unroll
  for (int ni = 0; ni < 4; ++ni) {
    const int n = (int)n0 + wn * 64 + ni * 16 + r15;
    float a1v[4];
#pragma unroll
    for (int s = 0; s < 4; ++s) {
      const float hv = b2f(h1c[(size_t)(bbase + s) * 1024 + n]);
      a1v[s] = 1.f - hv * hv;
    }
#pragma unroll
    for (int mi = 0; mi < 8; ++mi)
#pragma unroll
      for (int r = 0; r < 4; ++r) {
        const size_t m = m0 + wm * 128 + mi * 16 + q4 * 4 + r;
        T1[m * N + n] = f2b(a1v[mi >> 1] * acc[mi][ni][r]);
      }
  }
}

// ---------------------------------------------------------------- jvp2 + t0(next)
// blocks [0,njvp): trace atomics into out2; rest: t0 for the NEXT chunk.
__global__ __launch_bounds__(256, 2) void jvp2_t0_k(const bf* __restrict__ T1,
                                                    const bf* __restrict__ W2b,
                                                    const bf* __restrict__ W3b,
                                                    const bf* __restrict__ h2c,
                                                    float* __restrict__ out2c,
                                                    const bf* __restrict__ h0n,
                                                    const bf* __restrict__ W0T,
                                                    bf* __restrict__ T0,
                                                    int njvp) {
  __shared__ __align__(16) bf smem[24576];
  const int f = blockIdx.x;
  if (f >= njvp) { t0_body(f - njvp, h0n, W0T, T0); return; }
  const int t = threadIdx.x, l = t & 63, w = t >> 6;
  const int wm = w >> 1, wn = w & 1;
  const int n_t = (f >> 3) & 7, m_t = (f & 7) + 8 * (f >> 6);
  const size_t m0 = (size_t)m_t * 256, n0 = (size_t)n_t * 128;
  const int r15 = l & 15, q4 = l >> 4;
  f32x4 acc[8][4] = {};
  gemm_core(smem, smem + 16384, T1, W2b, m0, n0, acc);
  const int bbase = (int)((m0 + wm * 128) >> 5);
  float part[4] = {0.f, 0.f, 0.f, 0.f};
#pragma unroll
  for (int ni = 0; ni < 4; ++ni) {
    const int n = (int)n0 + wn * 64 + ni * 16 + r15;  // = p
    float a2v[4];
#pragma unroll
    for (int s = 0; s < 4; ++s) {
      const float hv = b2f(h2c[(size_t)(bbase + s) * 1024 + n]);
      a2v[s] = 1.f - hv * hv;
    }
#pragma unroll
    for (int mi = 0; mi < 8; ++mi) {
      const int isel = mi >> 1;
#pragma unroll
      for (int r = 0; r < 4; ++r) {
        const int mm = wm * 128 + mi * 16 + q4 * 4 + r;  // i = mm & 31
        part[isel] += b2f(W3b[(size_t)(mm & 31) * 1024 + n]) * a2v[isel] * acc[mi][ni][r];
      }
    }
  }
#pragma unroll
  for (int off = 32; off > 0; off >>= 1) {
#pragma unroll
    for (int s = 0; s < 4; ++s) part[s] += __shfl_down(part[s], off);
  }
  if (l == 0) {
#pragma unroll
    for (int s = 0; s < 4; ++s) atomicAdd(out2c + bbase + s, -part[s]);
  }
}

// ================================================================ launch
extern "C" void kernel_launch(void* const* d_in, const int* in_sizes, int n_in,
                              void* d_out, int out_size, void* d_ws, size_t ws_size,
                              hipStream_t stream) {
  const float* tin = (const float*)d_in[0];
  const float* z   = (const float*)d_in[1];
  const float* W0  = (const float*)d_in[2];
  const float* b0  = (const float*)d_in[3];
  const float* W1  = (const float*)d_in[4];
  const float* b1  = (const float*)d_in[5];
  const float* W2  = (const float*)d_in[6];
  const float* b2  = (const float*)d_in[7];
  const float* W3  = (const float*)d_in[8];
  const float* b3  = (const float*)d_in[9];
  float* out = (float*)d_out;
  float* out2 = out + 131072;  // divv region, zeroed by prep
  (void)in_sizes; (void)n_in; (void)out_size;

  char* ws = (char*)d_ws;
  size_t off = 0;
  auto take = [&](size_t bytes) {
    char* p = ws + off;
    off = (off + bytes + 255) & ~(size_t)255;
    return p;
  };
  bf* h0   = (bf*)take((size_t)4096 * 1024 * 2);   // 8 MB
  bf* h1   = (bf*)take((size_t)4096 * 1024 * 2);   // 8 MB
  bf* h2   = (bf*)take((size_t)4096 * 1024 * 2);   // 8 MB
  bf* W0T  = (bf*)take((size_t)32 * 1024 * 2);     // 64 KB
  bf* W1b  = (bf*)take((size_t)1024 * 1024 * 2);   // 2 MB
  bf* W2b  = (bf*)take((size_t)1024 * 1024 * 2);   // 2 MB
  bf* W3b  = (bf*)take((size_t)32 * 1024 * 2);     // 64 KB
  // chunk size: T0 + T1, each NB*32*1024*2 bytes
  const size_t avail = (ws_size > off) ? (ws_size - off) : 0;
  int NB = 4096;
  while (NB > 256 && 2 * (size_t)NB * 65536 > avail) NB >>= 1;
  bf* T0 = (bf*)take((size_t)NB * 65536);
  bf* T1 = (bf*)take((size_t)NB * 65536);

  // 1: prep (fwd0 + weight converts + zero divv region)
  prep_k<<<dim3(2337), dim3(256), 0, stream>>>(z, tin, W0, b0, W1, W2, W3,
                                               h0, W0T, W1b, W2b, W3b, out2);
  // 2: fwd1 (h0->h1) + t0 chunk0 on the otherwise-idle CUs
  fwd_t0_k<<<dim3(128 + NB * 8), dim3(256), 0, stream>>>(h0, W1b, b1, h1,
                                                         h0, W0T, T0);
  // 3: fwd2 (h1->h2), no t0 blocks
  fwd_t0_k<<<dim3(128), dim3(256), 0, stream>>>(h1, W2b, b2, h2, h0, W0T, T0);
  // 4..: jvp chunks
  const int nchunk = 4096 / NB;
  for (int c = 0; c < nchunk; ++c) {
    const int cb = c * NB;
    const int g1 = (c == 0) ? NB + 512 : NB;   // fwd3 rides on chunk 0
    jvp1_fwd3_k<<<dim3(g1), dim3(256), 0, stream>>>(
        T0, W1b, h1 + (size_t)cb * 1024, T1, h2, W3b, b3, out, NB);
    if (c + 1 < nchunk) {
      jvp2_t0_k<<<dim3(NB + NB * 8), dim3(256), 0, stream>>>(
          T1, W2b, W3b, h2 + (size_t)cb * 1024, out2 + cb,
          h0 + (size_t)(cb + NB) * 1024, W0T, T0, NB);
    } else {
      jvp2_t0_k<<<dim3(NB), dim3(256), 0, stream>>>(
          T1, W2b, W3b, h2 + (size_t)cb * 1024, out2 + cb,
          h0, W0T, T0, NB);
    }
  }
}

// Round 12
// 819.582 us; speedup vs baseline: 1.0656x; 1.0433x over previous
//
#include <hip/hip_runtime.h>
#include <hip/hip_bf16.h>
#include <stdint.h>

// CNF step: 4-layer tanh MLP (33->1024->1024->1024->32) forward + exact
// Jacobian trace via 32 forward-mode tangents. B=4096, H=1024, D=32.
// f32 in/out; bf16 MFMA internally.
//
// R12: LDS-pipe relief. Per-CU K-tile accounting of the R9 core: MFMA 588
// cyc vs LDS 768 read + 384 write = ~70% DS-pipe busy -> LDS binds, not
// MFMA. Staging via global_load_lds (16B) moves the LDS fill to the TA
// port (no ds_write instructions) and frees ~48 VGPR. XOR swizzle moves to
// the GLOBAL address (R4-validated): lane l stages seg (l&7)^(l>>3) of row
// u*8+(l>>3); since row&7==l>>3, LDS[row][s]=global[row][s^(row&7)], which
// is exactly the R9 conflict-free read pattern sa=(kk*4+q4)^(r15&7).
// R11 lesson: dispatch-count fusion is neutral; rider blocks serialize as
// tails -> t0/fwd3 standalone again. prep fusion + divv-in-jvp2 kept.

using bf  = __hip_bfloat16;
using bf2 = __hip_bfloat162;
typedef __attribute__((ext_vector_type(8))) short bf16x8;   // 8 bf16 = 4 VGPRs
typedef __attribute__((ext_vector_type(4))) float f32x4;    // C/D frag

__device__ __forceinline__ float b2f(bf x)    { return __bfloat162float(x); }
__device__ __forceinline__ bf    f2b(float x) { return __float2bfloat16(x); }

__device__ __forceinline__ void gld16(const void* g, void* l) {
  __builtin_amdgcn_global_load_lds((const __attribute__((address_space(1))) void*)g,
                                   (__attribute__((address_space(3))) void*)l,
                                   16, 0, 0);
}

// ---------------------------------------------------------------- small bodies
__device__ __forceinline__ void conv_body(int blk, const float* __restrict__ src,
                                          bf* __restrict__ dst, int n4) {
  const int i = blk * 256 + threadIdx.x;
  if (i >= n4) return;
  float4 v = ((const float4*)src)[i];
  bf2* d = (bf2*)(dst + (size_t)i * 4);
  d[0] = __float22bfloat162_rn(make_float2(v.x, v.y));
  d[1] = __float22bfloat162_rn(make_float2(v.z, v.w));
}

__device__ __forceinline__ void w0t_body(int blk, const float* __restrict__ W0,
                                         bf* __restrict__ W0T) {
  const int idx = blk * 256 + threadIdx.x;
  const int i = idx >> 10, q = idx & 1023;
  W0T[idx] = f2b(W0[q * 33 + i]);
}

// ---------------------------------------------------------------- prep
// [0,128): fwd0 | [128,1152): conv W1 | [1152,2176): conv W2
// [2176,2208): conv W3 | [2208,2336): W0T | 2336: zero divv region
__global__ __launch_bounds__(256) void prep_k(const float* __restrict__ z,
                                              const float* __restrict__ tin,
                                              const float* __restrict__ W0,
                                              const float* __restrict__ b0,
                                              const float* __restrict__ W1,
                                              const float* __restrict__ W2,
                                              const float* __restrict__ W3,
                                              bf* __restrict__ h0,
                                              bf* __restrict__ W0T,
                                              bf* __restrict__ W1b,
                                              bf* __restrict__ W2b,
                                              bf* __restrict__ W3b,
                                              float* __restrict__ out2) {
  __shared__ float zs[32 * 33];
  const int f = blockIdx.x, t = threadIdx.x;
  if (f < 128) {  // fwd0: 32 samples/block
    const int s0 = f * 32;
    for (int j = t; j < 1024; j += 256) {
      const int s = j >> 5, k = j & 31;
      zs[s * 33 + k] = z[(size_t)(s0 + s) * 32 + k];
    }
    if (t < 32) zs[t * 33 + 32] = tin[0];
    __syncthreads();
#pragma unroll 1
    for (int rep = 0; rep < 4; ++rep) {
      const int hh = rep * 256 + t;
      const float* wr = W0 + (size_t)hh * 33;
      float wv[33];
#pragma unroll
      for (int k = 0; k < 33; ++k) wv[k] = wr[k];
      const float bv = b0[hh];
#pragma unroll 1
      for (int s = 0; s < 32; ++s) {
        float acc = bv;
#pragma unroll
        for (int k = 0; k < 33; ++k) acc += wv[k] * zs[s * 33 + k];
        h0[(size_t)(s0 + s) * 1024 + hh] = f2b(tanhf(acc));
      }
    }
  } else if (f < 1152) {
    conv_body(f - 128, W1, W1b, 262144);
  } else if (f < 2176) {
    conv_body(f - 1152, W2, W2b, 262144);
  } else if (f < 2208) {
    conv_body(f - 2176, W3, W3b, 8192);
  } else if (f < 2336) {
    w0t_body(f - 2208, W0, W0T);
  } else {
#pragma unroll
    for (int u = 0; u < 16; ++u) out2[u * 256 + t] = 0.f;
  }
}

// ---------------------------------------------------------------- GEMM core
// 256x128 block, 128x64 wave-tile (8x4 frags), BK=64, glds(16B) staging with
// global-side XOR swizzle -> conflict-free reads, no ds_write instructions.
__device__ __forceinline__ void gemm_core(bf* As, bf* Bs,
                                          const bf* __restrict__ A,
                                          const bf* __restrict__ B,
                                          size_t m0, size_t n0,
                                          f32x4 (&acc)[8][4]) {
  constexpr int K = 1024;
  const int t = threadIdx.x, l = t & 63, w = t >> 6;
  const int wm = w >> 1, wn = w & 1;
  const int r15 = l & 15, q4 = l >> 4, sw = r15 & 7;

  // staging geometry: lane l covers row sub-index l>>3, seg (l&7)^(l>>3)
  const int lrow = l >> 3;
  const int lseg = (l & 7) ^ lrow;
  const bf* asrc[8]; bf* alds[8];
  const bf* bsrc[4]; bf* blds[4];
#pragma unroll
  for (int u = 0; u < 8; ++u) {
    const int row = w * 64 + u * 8 + lrow;           // A rows [w*64, w*64+64)
    asrc[u] = A + (m0 + row) * K + lseg * 8;
    alds[u] = As + (size_t)(w * 64 + u * 8) * 64;    // wave-uniform base
  }
#pragma unroll
  for (int u = 0; u < 4; ++u) {
    const int row = w * 32 + u * 8 + lrow;           // B rows [w*32, w*32+32)
    bsrc[u] = B + (n0 + row) * K + lseg * 8;
    blds[u] = Bs + (size_t)(w * 32 + u * 8) * 64;
  }

#pragma unroll 1
  for (int k0 = 0; k0 < K; k0 += 64) {
#pragma unroll
    for (int u = 0; u < 8; ++u) gld16(asrc[u] + k0, alds[u]);
#pragma unroll
    for (int u = 0; u < 4; ++u) gld16(bsrc[u] + k0, blds[u]);
    __syncthreads();
#pragma unroll
    for (int kk = 0; kk < 2; ++kk) {
      const int sa = (kk * 4 + q4) ^ sw;
      bf16x8 af[8], bfr[4];
#pragma unroll
      for (int i = 0; i < 8; ++i)
        af[i] = *(const bf16x8*)(As + (wm * 128 + i * 16 + r15) * 64 + sa * 8);
#pragma unroll
      for (int j = 0; j < 4; ++j)
        bfr[j] = *(const bf16x8*)(Bs + (wn * 64 + j * 16 + r15) * 64 + sa * 8);
#pragma unroll
      for (int mi = 0; mi < 8; ++mi)
#pragma unroll
        for (int ni = 0; ni < 4; ++ni)
          acc[mi][ni] = __builtin_amdgcn_mfma_f32_16x16x32_bf16(af[mi], bfr[ni], acc[mi][ni], 0, 0, 0);
    }
    __syncthreads();
  }
}

// ---------------------------------------------------------------- fwd GEMM
__global__ __launch_bounds__(256, 2) void gemm_fwd(const bf* __restrict__ A,
                                                   const bf* __restrict__ W,
                                                   const float* __restrict__ bias,
                                                   bf* __restrict__ H) {
  constexpr int N = 1024;
  __shared__ __align__(16) bf As[256 * 64];
  __shared__ __align__(16) bf Bs[128 * 64];
  const int t = threadIdx.x, l = t & 63, w = t >> 6;
  const int wm = w >> 1, wn = w & 1;
  const int f = blockIdx.x;                   // 128 blocks: 16 m x 8 n
  const int n_t = (f >> 3) & 7, m_t = (f & 7) + 8 * (f >> 6);
  const size_t m0 = (size_t)m_t * 256, n0 = (size_t)n_t * 128;
  const int r15 = l & 15, q4 = l >> 4;
  f32x4 acc[8][4] = {};
  gemm_core(As, Bs, A, W, m0, n0, acc);
#pragma unroll
  for (int ni = 0; ni < 4; ++ni) {
    const int n = (int)n0 + wn * 64 + ni * 16 + r15;
    const float bv = bias[n];
#pragma unroll
    for (int mi = 0; mi < 8; ++mi)
#pragma unroll
      for (int r = 0; r < 4; ++r) {
        const size_t m = m0 + wm * 128 + mi * 16 + q4 * 4 + r;
        H[m * N + n] = f2b(tanhf(acc[mi][ni][r] + bv));
      }
  }
}

// ---------------------------------------------------------------- fwd3 (out)
__global__ __launch_bounds__(256) void fwd3_k(const bf* __restrict__ h2,
                                              const bf* __restrict__ W3b,
                                              const float* __restrict__ b3,
                                              float* __restrict__ out) {
  __shared__ __align__(16) bf hs[8 * 1024];
  const int t = threadIdx.x;
  const size_t bb = (size_t)blockIdx.x * 8;
  const uint4* src = (const uint4*)(h2 + bb * 1024);
  uint4* dv = (uint4*)hs;
#pragma unroll
  for (int j = 0; j < 4; ++j) dv[j * 256 + t] = src[j * 256 + t];
  __syncthreads();
  const int i = t & 31, bl = t >> 5;
  const bf2* hr = (const bf2*)(hs + bl * 1024);
  const bf2* wr = (const bf2*)(W3b + (size_t)i * 1024);
  float s = 0.f;
#pragma unroll 8
  for (int k2 = 0; k2 < 512; ++k2) {
    float2 a = __bfloat1622float2(hr[k2]);
    float2 c = __bfloat1622float2(wr[k2]);
    s += a.x * c.x + a.y * c.y;
  }
  out[(bb + bl) * 32 + i] = s + b3[i];
}

// ---------------------------------------------------------------- t0 build
__global__ __launch_bounds__(256) void t0_k(const bf* __restrict__ h0c,
                                            const bf* __restrict__ W0T,
                                            bf* __restrict__ T0) {
  const int idx = blockIdx.x * 256 + threadIdx.x;
  const int m = idx >> 6, seg = idx & 63;
  const int b = m >> 5, i = m & 31;
  const bf2* hp = (const bf2*)(h0c + (size_t)b * 1024 + seg * 16);
  const bf2* wp = (const bf2*)(W0T + (size_t)i * 1024 + seg * 16);
  bf2* dp = (bf2*)(T0 + (size_t)m * 1024 + seg * 16);
#pragma unroll
  for (int u = 0; u < 8; ++u) {
    float2 h = __bfloat1622float2(hp[u]);
    float2 w = __bfloat1622float2(wp[u]);
    float2 r;
    r.x = (1.f - h.x * h.x) * w.x;
    r.y = (1.f - h.y * h.y) * w.y;
    dp[u] = __float22bfloat162_rn(r);
  }
}

// ---------------------------------------------------------------- jvp1
__global__ __launch_bounds__(256, 2) void gemm_jvp1(const bf* __restrict__ T0,
                                                    const bf* __restrict__ W1b,
                                                    const bf* __restrict__ h1c,
                                                    bf* __restrict__ T1) {
  constexpr int N = 1024;
  __shared__ __align__(16) bf As[256 * 64];
  __shared__ __align__(16) bf Bs[128 * 64];
  const int t = threadIdx.x, l = t & 63, w = t >> 6;
  const int wm = w >> 1, wn = w & 1;
  const int f = blockIdx.x;
  const int n_t = (f >> 3) & 7, m_t = (f & 7) + 8 * (f >> 6);
  const size_t m0 = (size_t)m_t * 256, n0 = (size_t)n_t * 128;
  const int r15 = l & 15, q4 = l >> 4;
  f32x4 acc[8][4] = {};
  gemm_core(As, Bs, T0, W1b, m0, n0, acc);
  const int bbase = (int)((m0 + wm * 128) >> 5);  // 4 samples per wave
#pragma unroll
  for (int ni = 0; ni < 4; ++ni) {
    const int n = (int)n0 + wn * 64 + ni * 16 + r15;
    float a1v[4];
#pragma unroll
    for (int s = 0; s < 4; ++s) {
      const float hv = b2f(h1c[(size_t)(bbase + s) * 1024 + n]);
      a1v[s] = 1.f - hv * hv;
    }
#pragma unroll
    for (int mi = 0; mi < 8; ++mi)
#pragma unroll
      for (int r = 0; r < 4; ++r) {
        const size_t m = m0 + wm * 128 + mi * 16 + q4 * 4 + r;
        T1[m * N + n] = f2b(a1v[mi >> 1] * acc[mi][ni][r]);
      }
  }
}

// ---------------------------------------------------------------- jvp2
__global__ __launch_bounds__(256, 2) void gemm_jvp2(const bf* __restrict__ T1,
                                                    const bf* __restrict__ W2b,
                                                    const bf* __restrict__ W3b,
                                                    const bf* __restrict__ h2c,
                                                    float* __restrict__ out2c) {
  __shared__ __align__(16) bf As[256 * 64];
  __shared__ __align__(16) bf Bs[128 * 64];
  const int t = threadIdx.x, l = t & 63, w = t >> 6;
  const int wm = w >> 1, wn = w & 1;
  const int f = blockIdx.x;
  const int n_t = (f >> 3) & 7, m_t = (f & 7) + 8 * (f >> 6);
  const size_t m0 = (size_t)m_t * 256, n0 = (size_t)n_t * 128;
  const int r15 = l & 15, q4 = l >> 4;
  f32x4 acc[8][4] = {};
  gemm_core(As, Bs, T1, W2b, m0, n0, acc);
  const int bbase = (int)((m0 + wm * 128) >> 5);  // 4 samples per wave
  float part[4] = {0.f, 0.f, 0.f, 0.f};
#pragma unroll
  for (int ni = 0; ni < 4; ++ni) {
    const int n = (int)n0 + wn * 64 + ni * 16 + r15;  // = p
    float a2v[4];
#pragma unroll
    for (int s = 0; s < 4; ++s) {
      const float hv = b2f(h2c[(size_t)(bbase + s) * 1024 + n]);
      a2v[s] = 1.f - hv * hv;
    }
#pragma unroll
    for (int mi = 0; mi < 8; ++mi) {
      const int isel = mi >> 1;
#pragma unroll
      for (int r = 0; r < 4; ++r) {
        const int mm = wm * 128 + mi * 16 + q4 * 4 + r;  // i = mm & 31
        part[isel] += b2f(W3b[(size_t)(mm & 31) * 1024 + n]) * a2v[isel] * acc[mi][ni][r];
      }
    }
  }
#pragma unroll
  for (int off = 32; off > 0; off >>= 1) {
#pragma unroll
    for (int s = 0; s < 4; ++s) part[s] += __shfl_down(part[s], off);
  }
  if (l == 0) {
#pragma unroll
    for (int s = 0; s < 4; ++s) atomicAdd(out2c + bbase + s, -part[s]);
  }
}

// ================================================================ launch
extern "C" void kernel_launch(void* const* d_in, const int* in_sizes, int n_in,
                              void* d_out, int out_size, void* d_ws, size_t ws_size,
                              hipStream_t stream) {
  const float* tin = (const float*)d_in[0];
  const float* z   = (const float*)d_in[1];
  const float* W0  = (const float*)d_in[2];
  const float* b0  = (const float*)d_in[3];
  const float* W1  = (const float*)d_in[4];
  const float* b1  = (const float*)d_in[5];
  const float* W2  = (const float*)d_in[6];
  const float* b2  = (const float*)d_in[7];
  const float* W3  = (const float*)d_in[8];
  const float* b3  = (const float*)d_in[9];
  float* out = (float*)d_out;
  float* out2 = out + 131072;  // divv region, zeroed by prep
  (void)in_sizes; (void)n_in; (void)out_size;

  char* ws = (char*)d_ws;
  size_t off = 0;
  auto take = [&](size_t bytes) {
    char* p = ws + off;
    off = (off + bytes + 255) & ~(size_t)255;
    return p;
  };
  bf* h0   = (bf*)take((size_t)4096 * 1024 * 2);   // 8 MB
  bf* h1   = (bf*)take((size_t)4096 * 1024 * 2);   // 8 MB
  bf* h2   = (bf*)take((size_t)4096 * 1024 * 2);   // 8 MB
  bf* W0T  = (bf*)take((size_t)32 * 1024 * 2);     // 64 KB
  bf* W1b  = (bf*)take((size_t)1024 * 1024 * 2);   // 2 MB
  bf* W2b  = (bf*)take((size_t)1024 * 1024 * 2);   // 2 MB
  bf* W3b  = (bf*)take((size_t)32 * 1024 * 2);     // 64 KB
  const size_t avail = (ws_size > off) ? (ws_size - off) : 0;
  int NB = 4096;
  while (NB > 256 && 2 * (size_t)NB * 65536 > avail) NB >>= 1;
  bf* T0 = (bf*)take((size_t)NB * 65536);
  bf* T1 = (bf*)take((size_t)NB * 65536);

  prep_k<<<dim3(2337), dim3(256), 0, stream>>>(z, tin, W0, b0, W1, W2, W3,
                                               h0, W0T, W1b, W2b, W3b, out2);
  gemm_fwd<<<dim3(128), dim3(256), 0, stream>>>(h0, W1b, b1, h1);
  gemm_fwd<<<dim3(128), dim3(256), 0, stream>>>(h1, W2b, b2, h2);
  fwd3_k<<<dim3(512), dim3(256), 0, stream>>>(h2, W3b, b3, out);
  for (int cb = 0; cb < 4096; cb += NB) {
    t0_k<<<dim3(NB * 8), dim3(256), 0, stream>>>(h0 + (size_t)cb * 1024, W0T, T0);
    gemm_jvp1<<<dim3(NB), dim3(256), 0, stream>>>(
        T0, W1b, h1 + (size_t)cb * 1024, T1);
    gemm_jvp2<<<dim3(NB), dim3(256), 0, stream>>>(
        T1, W2b, W3b, h2 + (size_t)cb * 1024, out2 + cb);
  }
}